// Round 1
// baseline (27849.814 us; speedup 1.0000x reference)
//
#include <hip/hip_runtime.h>
#include <hip/hip_bf16.h>
#include <math.h>

// Problem constants
#define BB 4
#define SS 2048
#define DM 1024
#define NH 8
#define DH 128
#define NE 8
#define NTOK (BB*SS)          // 8192
// scale_sqrt = DH^-0.25 applied to both q and k
#define SCALE_SQRT 0.29730177875068026f

// ---------------------------------------------------------------------------
// Projection GEMM: out[b,h,s,f] = scale * sum_d A[token,d] * W[h*128+f, d]
// A: [8192,1024] row-major, W: [1024,1024] row-major (output-major like torch)
// 64x64 tile, 256 threads, 4x4 per thread, fp32.
// ---------------------------------------------------------------------------
__global__ void proj_kernel(const float* __restrict__ A,
                            const float* __restrict__ W,
                            float* __restrict__ out, float scale) {
    __shared__ float As[16][65];   // [k][m]
    __shared__ float Ws[16][65];   // [k][n]
    const int t  = threadIdx.x;          // 0..255
    const int tx = t & 15, ty = t >> 4;  // 16x16 thread grid
    const int m0 = blockIdx.x * 64, n0 = blockIdx.y * 64;
    float acc[4][4] = {};
    for (int kt = 0; kt < DM; kt += 16) {
#pragma unroll
        for (int i = 0; i < 4; ++i) {
            int idx = t + i * 256;           // 0..1023
            int m = idx >> 4, kk = idx & 15;
            As[kk][m] = A[(size_t)(m0 + m) * DM + kt + kk];
            Ws[kk][m] = W[(size_t)(n0 + m) * DM + kt + kk];
        }
        __syncthreads();
#pragma unroll
        for (int kk = 0; kk < 16; ++kk) {
            float a[4], b[4];
#pragma unroll
            for (int i = 0; i < 4; ++i) a[i] = As[kk][ty * 4 + i];
#pragma unroll
            for (int j = 0; j < 4; ++j) b[j] = Ws[kk][tx * 4 + j];
#pragma unroll
            for (int i = 0; i < 4; ++i)
#pragma unroll
                for (int j = 0; j < 4; ++j) acc[i][j] += a[i] * b[j];
        }
        __syncthreads();
    }
#pragma unroll
    for (int ii = 0; ii < 4; ++ii)
#pragma unroll
        for (int jj = 0; jj < 4; ++jj) {
            int i = m0 + ty * 4 + ii;     // token = b*S+s
            int j = n0 + tx * 4 + jj;     // h*128+f
            int b = i >> 11, s = i & 2047, h = j >> 7, f = j & 127;
            out[((((size_t)(b * NH + h)) * SS + s) << 7) + f] = acc[ii][jj] * scale;
        }
}

// ---------------------------------------------------------------------------
// Gate: logits[token,he] = x[token,:].sel[he,:]; sigmoid; top-1 over e in
// [0,7) + shared e=7. One block (64 threads) per token.
// ---------------------------------------------------------------------------
__global__ void gate_kernel(const float* __restrict__ x,
                            const float* __restrict__ sel,
                            int* __restrict__ idxArr,
                            float* __restrict__ g1Arr,
                            float* __restrict__ g2Arr) {
    __shared__ float xs[DM];
    __shared__ float logits[64];
    const int token = blockIdx.x;
    const int t = threadIdx.x;  // 0..63
    const float* xp = x + (size_t)token * DM;
    for (int i = t; i < DM; i += 64) xs[i] = xp[i];
    __syncthreads();
    const float* sp = sel + (size_t)t * DM;
    float acc = 0.f;
    for (int d = 0; d < DM; ++d) acc += xs[d] * sp[d];
    logits[t] = acc;
    __syncthreads();
    if (t < NH) {
        const int h = t;
        const float* lp = logits + h * NE;
        int best = 0; float bv = lp[0];
#pragma unroll
        for (int e = 1; e < NE - 1; ++e)
            if (lp[e] > bv) { bv = lp[e]; best = e; }   // strict > == lowest idx tie
        float g1 = 1.f / (1.f + expf(-bv));
        float g2 = 1.f / (1.f + expf(-lp[NE - 1]));
        int gi = token * NH + h;
        idxArr[gi] = best; g1Arr[gi] = g1; g2Arr[gi] = g2;
    }
}

// ---------------------------------------------------------------------------
// Value CVMM: v[b,h,s,f] = g1 * (v_src[token,:] . V[h,e1,:,f])
//                        + g2 * (v_src[token,:] . V[h,7 ,:,f])
// Block = one (h, token); bid = h*8192 + token so concurrent blocks share h
// (keeps per-XCD L2 working set ~4 MB). 128 threads, one f each.
// ---------------------------------------------------------------------------
__global__ void v_kernel(const float* __restrict__ vsrc,
                         const float* __restrict__ V,
                         const int* __restrict__ gidx,
                         const float* __restrict__ g1a,
                         const float* __restrict__ g2a,
                         float* __restrict__ vout) {
    const int bid = blockIdx.x;
    const int h = bid >> 13;          // /8192
    const int token = bid & (NTOK - 1);
    __shared__ float xs[DM];
    const int t = threadIdx.x;  // 0..127
    const float* xp = vsrc + (size_t)token * DM;
    for (int i = t; i < DM; i += 128) xs[i] = xp[i];
    __syncthreads();
    const int gi = token * NH + h;
    const int e1 = gidx[gi];
    const float g1 = g1a[gi], g2 = g2a[gi];
    const float* V1 = V + ((size_t)(h * NE + e1) * DM) * DH;
    const float* V2 = V + ((size_t)(h * NE + (NE - 1)) * DM) * DH;
    float acc = 0.f;
    for (int d = 0; d < DM; ++d) {
        acc += xs[d] * (g1 * V1[(size_t)d * DH + t] + g2 * V2[(size_t)d * DH + t]);
    }
    const int b = token >> 11, s = token & 2047;
    vout[((((size_t)(b * NH + h)) * SS + s) << 7) + t] = acc;
}

// ---------------------------------------------------------------------------
// Attention: one block per (b,h,query). 256 threads.
// Pass 1: scores into LDS; max/sum reduce; Pass 2: PV.
// res layout: [B,S,H,F]
// ---------------------------------------------------------------------------
__global__ void attn_kernel(const float* __restrict__ q,
                            const float* __restrict__ k,
                            const float* __restrict__ v,
                            float* __restrict__ res) {
    const int bid = blockIdx.x;
    const int qi = bid & (SS - 1);
    const int bh = bid >> 11;            // b*8+h
    const float* qp = q + ((size_t)bh * SS + qi) * DH;
    const float* kp = k + (size_t)bh * SS * DH;
    const float* vp = v + (size_t)bh * SS * DH;
    __shared__ float qs[DH];
    __shared__ float sc[SS];
    __shared__ float red[256];
    const int t = threadIdx.x;
    if (t < DH) qs[t] = qp[t];
    __syncthreads();
    // scores
    for (int j = t; j < SS; j += 256) {
        const float* kr = kp + (size_t)j * DH;
        float acc = 0.f;
#pragma unroll 4
        for (int f = 0; f < DH; ++f) acc += qs[f] * kr[f];
        sc[j] = acc;
    }
    __syncthreads();
    // max reduction
    float m = -1e30f;
    for (int j = t; j < SS; j += 256) m = fmaxf(m, sc[j]);
    red[t] = m; __syncthreads();
    for (int s = 128; s > 0; s >>= 1) {
        if (t < s) red[t] = fmaxf(red[t], red[t + s]);
        __syncthreads();
    }
    m = red[0];
    __syncthreads();
    // exp + sum
    float sum = 0.f;
    for (int j = t; j < SS; j += 256) { float p = expf(sc[j] - m); sc[j] = p; sum += p; }
    red[t] = sum; __syncthreads();
    for (int s = 128; s > 0; s >>= 1) {
        if (t < s) red[t] += red[t + s];
        __syncthreads();
    }
    const float inv = 1.f / red[0];
    __syncthreads();   // everyone has read red[0] before red is reused below
    // PV: output (f, half) per thread
    const int f = t & (DH - 1), half = t >> 7;
    float acc = 0.f;
    const int j0 = half * (SS / 2), j1 = j0 + SS / 2;
    for (int j = j0; j < j1; ++j) acc += sc[j] * vp[(size_t)j * DH + f];
    red[t] = acc; __syncthreads();
    if (t < DH) {
        float r = (red[t] + red[t + DH]) * inv;
        const int b = bh >> 3, h = bh & 7;
        res[((((size_t)(b * SS + qi)) * NH + h) << 7) + f] = r;
    }
}

// ---------------------------------------------------------------------------
// Output CVMM: out[token,d] = sum_h [ g1 * (res[token,h,:] . O[h,e1,:,d])
//                                   + g2 * (res[token,h,:] . O[h,7 ,:,d]) ]
// Block per token, 256 threads, each handles d = jj*256 + t (coalesced).
// ---------------------------------------------------------------------------
__global__ void out_kernel(const float* __restrict__ res,
                           const float* __restrict__ O,
                           const int* __restrict__ gidx,
                           const float* __restrict__ g1a,
                           const float* __restrict__ g2a,
                           float* __restrict__ out) {
    const int token = blockIdx.x;
    __shared__ float rs[NH * DH];
    const int t = threadIdx.x;  // 0..255
    const float* rp = res + (size_t)token * NH * DH;
    for (int i = t; i < NH * DH; i += 256) rs[i] = rp[i];
    __syncthreads();
    float acc[4] = {0.f, 0.f, 0.f, 0.f};
    for (int h = 0; h < NH; ++h) {
        const int gi = token * NH + h;
        const int e1 = gidx[gi];
        const float g1 = g1a[gi], g2 = g2a[gi];
        const float* O1 = O + (size_t)(h * NE + e1) * DH * DM;
        const float* O2 = O + (size_t)(h * NE + (NE - 1)) * DH * DM;
        const float* rh = rs + h * DH;
        for (int f = 0; f < DH; ++f) {
            const float r1 = rh[f] * g1, r2 = rh[f] * g2;
            const size_t ro = (size_t)f * DM + t;
#pragma unroll
            for (int jj = 0; jj < 4; ++jj) {
                acc[jj] += r1 * O1[ro + jj * 256] + r2 * O2[ro + jj * 256];
            }
        }
    }
#pragma unroll
    for (int jj = 0; jj < 4; ++jj)
        out[(size_t)token * DM + jj * 256 + t] = acc[jj];
}

// ---------------------------------------------------------------------------
extern "C" void kernel_launch(void* const* d_in, const int* in_sizes, int n_in,
                              void* d_out, int out_size, void* d_ws, size_t ws_size,
                              hipStream_t stream) {
    (void)in_sizes; (void)n_in; (void)out_size; (void)ws_size;
    const float* q_src = (const float*)d_in[0];
    const float* k_src = (const float*)d_in[1];
    const float* v_src = (const float*)d_in[2];
    const float* Wq    = (const float*)d_in[3];
    const float* Wk    = (const float*)d_in[4];
    const float* V     = (const float*)d_in[5];
    const float* O     = (const float*)d_in[6];
    const float* sel_v = (const float*)d_in[7];
    const float* sel_o = (const float*)d_in[8];
    float* out = (float*)d_out;

    // workspace layout (fp32 elements)
    const size_t NELT = (size_t)NTOK * DM;   // 8388608
    float* wq   = (float*)d_ws;              // q  [B,H,S,F]
    float* wk   = wq + NELT;                 // k  [B,H,S,F]
    float* wv   = wk + NELT;                 // v  [B,H,S,F]
    float* wres = wv + NELT;                 // res[B,S,H,F]
    int*   gv_idx = (int*)(wres + NELT);
    float* gv_g1  = (float*)(gv_idx + NTOK * NH);
    float* gv_g2  = gv_g1 + NTOK * NH;
    int*   go_idx = (int*)(gv_g2 + NTOK * NH);
    float* go_g1  = (float*)(go_idx + NTOK * NH);
    float* go_g2  = go_g1 + NTOK * NH;

    // q/k projections
    dim3 pgrid(NTOK / 64, (NH * DH) / 64);
    proj_kernel<<<pgrid, 256, 0, stream>>>(q_src, Wq, wq, SCALE_SQRT);
    proj_kernel<<<pgrid, 256, 0, stream>>>(k_src, Wk, wk, SCALE_SQRT);

    // gates: gv from k_src/sel_v, go from q_src/sel_o
    gate_kernel<<<NTOK, 64, 0, stream>>>(k_src, sel_v, gv_idx, gv_g1, gv_g2);
    gate_kernel<<<NTOK, 64, 0, stream>>>(q_src, sel_o, go_idx, go_g1, go_g2);

    // value CVMM
    v_kernel<<<NTOK * NH, 128, 0, stream>>>(v_src, V, gv_idx, gv_g1, gv_g2, wv);

    // attention
    attn_kernel<<<BB * NH * SS, 256, 0, stream>>>(wq, wk, wv, wres);

    // output CVMM
    out_kernel<<<NTOK, 256, 0, stream>>>(wres, O, go_idx, go_g1, go_g2, out);
}

// Round 2
// 9857.597 us; speedup vs baseline: 2.8252x; 2.8252x over previous
//
#include <hip/hip_runtime.h>
#include <hip/hip_bf16.h>
#include <math.h>

// Problem constants
#define BB 4
#define SS 2048
#define DM 1024
#define NH 8
#define DH 128
#define NE 8
#define NTOK (BB*SS)          // 8192
// scale_sqrt = DH^-0.25 applied to both q and k
#define SCALE_SQRT 0.29730177875068026f

// ---------------------------------------------------------------------------
// Projection GEMM: out[b,h,s,f] = scale * sum_d A[token,d] * W[h*128+f, d]
// ---------------------------------------------------------------------------
__global__ void proj_kernel(const float* __restrict__ A,
                            const float* __restrict__ W,
                            float* __restrict__ out, float scale) {
    __shared__ float As[16][65];   // [k][m]
    __shared__ float Ws[16][65];   // [k][n]
    const int t  = threadIdx.x;          // 0..255
    const int tx = t & 15, ty = t >> 4;  // 16x16 thread grid
    const int m0 = blockIdx.x * 64, n0 = blockIdx.y * 64;
    float acc[4][4] = {};
    for (int kt = 0; kt < DM; kt += 16) {
#pragma unroll
        for (int i = 0; i < 4; ++i) {
            int idx = t + i * 256;           // 0..1023
            int m = idx >> 4, kk = idx & 15;
            As[kk][m] = A[(size_t)(m0 + m) * DM + kt + kk];
            Ws[kk][m] = W[(size_t)(n0 + m) * DM + kt + kk];
        }
        __syncthreads();
#pragma unroll
        for (int kk = 0; kk < 16; ++kk) {
            float a[4], b[4];
#pragma unroll
            for (int i = 0; i < 4; ++i) a[i] = As[kk][ty * 4 + i];
#pragma unroll
            for (int j = 0; j < 4; ++j) b[j] = Ws[kk][tx * 4 + j];
#pragma unroll
            for (int i = 0; i < 4; ++i)
#pragma unroll
                for (int j = 0; j < 4; ++j) acc[i][j] += a[i] * b[j];
        }
        __syncthreads();
    }
#pragma unroll
    for (int ii = 0; ii < 4; ++ii)
#pragma unroll
        for (int jj = 0; jj < 4; ++jj) {
            int i = m0 + ty * 4 + ii;     // token = b*S+s
            int j = n0 + tx * 4 + jj;     // h*128+f
            int b = i >> 11, s = i & 2047, h = j >> 7, f = j & 127;
            out[((((size_t)(b * NH + h)) * SS + s) << 7) + f] = acc[ii][jj] * scale;
        }
}

// ---------------------------------------------------------------------------
// Gate kernel (unchanged)
// ---------------------------------------------------------------------------
__global__ void gate_kernel(const float* __restrict__ x,
                            const float* __restrict__ sel,
                            int* __restrict__ idxArr,
                            float* __restrict__ g1Arr,
                            float* __restrict__ g2Arr) {
    __shared__ float xs[DM];
    __shared__ float logits[64];
    const int token = blockIdx.x;
    const int t = threadIdx.x;  // 0..63
    const float* xp = x + (size_t)token * DM;
    for (int i = t; i < DM; i += 64) xs[i] = xp[i];
    __syncthreads();
    const float* sp = sel + (size_t)t * DM;
    float acc = 0.f;
    for (int d = 0; d < DM; ++d) acc += xs[d] * sp[d];
    logits[t] = acc;
    __syncthreads();
    if (t < NH) {
        const int h = t;
        const float* lp = logits + h * NE;
        int best = 0; float bv = lp[0];
#pragma unroll
        for (int e = 1; e < NE - 1; ++e)
            if (lp[e] > bv) { bv = lp[e]; best = e; }
        float g1 = 1.f / (1.f + expf(-bv));
        float g2 = 1.f / (1.f + expf(-lp[NE - 1]));
        int gi = token * NH + h;
        idxArr[gi] = best; g1Arr[gi] = g1; g2Arr[gi] = g2;
    }
}

// ---------------------------------------------------------------------------
// Value CVMM (unchanged this round)
// ---------------------------------------------------------------------------
__global__ void v_kernel(const float* __restrict__ vsrc,
                         const float* __restrict__ V,
                         const int* __restrict__ gidx,
                         const float* __restrict__ g1a,
                         const float* __restrict__ g2a,
                         float* __restrict__ vout) {
    const int bid = blockIdx.x;
    const int h = bid >> 13;          // /8192
    const int token = bid & (NTOK - 1);
    __shared__ float xs[DM];
    const int t = threadIdx.x;  // 0..127
    const float* xp = vsrc + (size_t)token * DM;
    for (int i = t; i < DM; i += 128) xs[i] = xp[i];
    __syncthreads();
    const int gi = token * NH + h;
    const int e1 = gidx[gi];
    const float g1 = g1a[gi], g2 = g2a[gi];
    const float* V1 = V + ((size_t)(h * NE + e1) * DM) * DH;
    const float* V2 = V + ((size_t)(h * NE + (NE - 1)) * DM) * DH;
    float acc = 0.f;
    for (int d = 0; d < DM; ++d) {
        acc += xs[d] * (g1 * V1[(size_t)d * DH + t] + g2 * V2[(size_t)d * DH + t]);
    }
    const int b = token >> 11, s = token & 2047;
    vout[((((size_t)(b * NH + h)) * SS + s) << 7) + t] = acc;
}

// ---------------------------------------------------------------------------
// Flash-style attention, fp32.
// One block = one (b,h) x 64-query tile. 256 threads (16x16).
// K-tiles of 32 staged in LDS; online softmax; register O accumulator.
//   Qs[f][i]  : Q tile transposed, 128x64   (32 KB)
//   KPbuf     : Ks[f][j] (128x32, 16 KB) aliased with Ps[j][i] (32x68 floats)
//   Vs[j][f]  : V tile natural, 32x128      (16 KB)
// Score phase: thread (tx,ty) owns rows i=4ty..4ty+3, cols j=2tx..2tx+1.
// PV phase:    thread (tx,ty) owns rows i=4ty..4ty+3, cols c=8tx..8tx+7.
// ---------------------------------------------------------------------------
#define QT 64
#define KT 32

__global__ __launch_bounds__(256, 2) void attn_kernel(
        const float* __restrict__ q,
        const float* __restrict__ k,
        const float* __restrict__ v,
        float* __restrict__ res) {
    const int bid = blockIdx.x;          // bh*32 + qtile  (consecutive blocks share K/V)
    const int bh = bid >> 5;
    const int q0 = (bid & 31) * QT;

    __shared__ float Qs[DH][QT];         // [f][i]
    __shared__ float KPbuf[DH * KT];     // Ks[f*KT+j]  /  Ps[j*68+i]
    __shared__ float Vs[KT][DH];         // [j][f]
    __shared__ float mArr[QT], lArr[QT], aArr[QT];
    __shared__ float red[4][QT];

    const int t = threadIdx.x;
    const int tx = t & 15, ty = t >> 4;

    // ---- load Q tile (transposed into LDS) ----
    const float* qp = q + ((size_t)bh * SS + q0) * DH;
#pragma unroll
    for (int r = 0; r < 8; ++r) {
        int idx = r * 256 + t;           // 0..2047
        int i = idx >> 5;                // row 0..63
        int f4 = (idx & 31) << 2;        // 0..124
        float4 qv = *(const float4*)(qp + (size_t)i * DH + f4);
        Qs[f4 + 0][i] = qv.x; Qs[f4 + 1][i] = qv.y;
        Qs[f4 + 2][i] = qv.z; Qs[f4 + 3][i] = qv.w;
    }
    if (t < QT) { mArr[t] = -INFINITY; lArr[t] = 0.f; }

    float O[4][8];
#pragma unroll
    for (int ii = 0; ii < 4; ++ii)
#pragma unroll
        for (int cc = 0; cc < 8; ++cc) O[ii][cc] = 0.f;

    const float* kbase = k + (size_t)bh * SS * DH;
    const float* vbase = v + (size_t)bh * SS * DH;

    for (int kt = 0; kt < SS / KT; ++kt) {
        __syncthreads();   // previous tile's KPbuf/Vs fully consumed
        // ---- stage K (transposed) and V (natural) tiles ----
        const float* kp = kbase + (size_t)kt * KT * DH;
        const float* vp = vbase + (size_t)kt * KT * DH;
#pragma unroll
        for (int r = 0; r < 4; ++r) {
            int idx = r * 256 + t;       // 0..1023
            int j = idx >> 5;            // 0..31
            int f4 = (idx & 31) << 2;
            float4 kv = *(const float4*)(kp + (size_t)j * DH + f4);
            KPbuf[(f4 + 0) * KT + j] = kv.x; KPbuf[(f4 + 1) * KT + j] = kv.y;
            KPbuf[(f4 + 2) * KT + j] = kv.z; KPbuf[(f4 + 3) * KT + j] = kv.w;
            float4 vv = *(const float4*)(vp + (size_t)j * DH + f4);
            *(float4*)&Vs[j][f4] = vv;
        }
        __syncthreads();

        // ---- scores: S[i][j] = sum_f Qs[f][i] * Ks[f][j] ----
        float s[4][2] = {};
#pragma unroll 8
        for (int f = 0; f < DH; ++f) {
            float4 a = *(const float4*)&Qs[f][ty * 4];
            float2 b = *(const float2*)&KPbuf[f * KT + tx * 2];
            s[0][0] += a.x * b.x; s[0][1] += a.x * b.y;
            s[1][0] += a.y * b.x; s[1][1] += a.y * b.y;
            s[2][0] += a.z * b.x; s[2][1] += a.z * b.y;
            s[3][0] += a.w * b.x; s[3][1] += a.w * b.y;
        }
        __syncthreads();   // done reading Ks; KPbuf reusable as Ps

        // ---- write S into Ps[j][i] (stride 68 keeps b128 reads aligned) ----
#pragma unroll
        for (int jj = 0; jj < 2; ++jj)
#pragma unroll
            for (int ii = 0; ii < 4; ++ii)
                KPbuf[(tx * 2 + jj) * 68 + ty * 4 + ii] = s[ii][jj];
        __syncthreads();

        // ---- row max + alpha (one thread per query row) ----
        if (t < QT) {
            float mx = -INFINITY;
#pragma unroll
            for (int j = 0; j < KT; ++j) mx = fmaxf(mx, KPbuf[j * 68 + t]);
            float mo = mArr[t];
            float mn = fmaxf(mo, mx);
            mArr[t] = mn;
            aArr[t] = __expf(mo - mn);   // 0 on first tile
        }
        __syncthreads();

        // ---- rescale O by alpha; exponentiate P; partial row sums ----
#pragma unroll
        for (int ii = 0; ii < 4; ++ii) {
            float al = aArr[ty * 4 + ii];
#pragma unroll
            for (int cc = 0; cc < 8; ++cc) O[ii][cc] *= al;
        }
        {
            int i = t & 63, jg = t >> 6;
            float mi = mArr[i];
            float sum = 0.f;
#pragma unroll
            for (int jj = 0; jj < 8; ++jj) {
                int j = jg * 8 + jj;
                float p = __expf(KPbuf[j * 68 + i] - mi);
                KPbuf[j * 68 + i] = p;
                sum += p;
            }
            red[jg][i] = sum;
        }
        __syncthreads();
        if (t < QT)
            lArr[t] = aArr[t] * lArr[t] + red[0][t] + red[1][t] + red[2][t] + red[3][t];

        // ---- PV: O[i][c] += P[i][j] * Vs[j][c] ----
#pragma unroll 4
        for (int j = 0; j < KT; ++j) {
            float4 p4 = *(const float4*)&KPbuf[j * 68 + ty * 4];
            float4 v0 = *(const float4*)&Vs[j][tx * 8];
            float4 v1 = *(const float4*)&Vs[j][tx * 8 + 4];
            float pv[4] = {p4.x, p4.y, p4.z, p4.w};
#pragma unroll
            for (int ii = 0; ii < 4; ++ii) {
                O[ii][0] += pv[ii] * v0.x; O[ii][1] += pv[ii] * v0.y;
                O[ii][2] += pv[ii] * v0.z; O[ii][3] += pv[ii] * v0.w;
                O[ii][4] += pv[ii] * v1.x; O[ii][5] += pv[ii] * v1.y;
                O[ii][6] += pv[ii] * v1.z; O[ii][7] += pv[ii] * v1.w;
            }
        }
    }
    __syncthreads();   // last lArr update visible

    // ---- epilogue: normalize and store res[b, s, h, f] ----
    const int b = bh >> 3, h = bh & 7;
#pragma unroll
    for (int ii = 0; ii < 4; ++ii) {
        float linv = 1.f / lArr[ty * 4 + ii];
        int qi = q0 + ty * 4 + ii;
        float* rp = res + ((((size_t)(b * SS + qi)) * NH + h) << 7) + tx * 8;
        float4 o0 = {O[ii][0] * linv, O[ii][1] * linv, O[ii][2] * linv, O[ii][3] * linv};
        float4 o1 = {O[ii][4] * linv, O[ii][5] * linv, O[ii][6] * linv, O[ii][7] * linv};
        *(float4*)(rp)     = o0;
        *(float4*)(rp + 4) = o1;
    }
}

// ---------------------------------------------------------------------------
// Output CVMM (unchanged this round)
// ---------------------------------------------------------------------------
__global__ void out_kernel(const float* __restrict__ res,
                           const float* __restrict__ O,
                           const int* __restrict__ gidx,
                           const float* __restrict__ g1a,
                           const float* __restrict__ g2a,
                           float* __restrict__ out) {
    const int token = blockIdx.x;
    __shared__ float rs[NH * DH];
    const int t = threadIdx.x;  // 0..255
    const float* rp = res + (size_t)token * NH * DH;
    for (int i = t; i < NH * DH; i += 256) rs[i] = rp[i];
    __syncthreads();
    float acc[4] = {0.f, 0.f, 0.f, 0.f};
    for (int h = 0; h < NH; ++h) {
        const int gi = token * NH + h;
        const int e1 = gidx[gi];
        const float g1 = g1a[gi], g2 = g2a[gi];
        const float* O1 = O + (size_t)(h * NE + e1) * DH * DM;
        const float* O2 = O + (size_t)(h * NE + (NE - 1)) * DH * DM;
        const float* rh = rs + h * DH;
        for (int f = 0; f < DH; ++f) {
            const float r1 = rh[f] * g1, r2 = rh[f] * g2;
            const size_t ro = (size_t)f * DM + t;
#pragma unroll
            for (int jj = 0; jj < 4; ++jj) {
                acc[jj] += r1 * O1[ro + jj * 256] + r2 * O2[ro + jj * 256];
            }
        }
    }
#pragma unroll
    for (int jj = 0; jj < 4; ++jj)
        out[(size_t)token * DM + jj * 256 + t] = acc[jj];
}

// ---------------------------------------------------------------------------
extern "C" void kernel_launch(void* const* d_in, const int* in_sizes, int n_in,
                              void* d_out, int out_size, void* d_ws, size_t ws_size,
                              hipStream_t stream) {
    (void)in_sizes; (void)n_in; (void)out_size; (void)ws_size;
    const float* q_src = (const float*)d_in[0];
    const float* k_src = (const float*)d_in[1];
    const float* v_src = (const float*)d_in[2];
    const float* Wq    = (const float*)d_in[3];
    const float* Wk    = (const float*)d_in[4];
    const float* V     = (const float*)d_in[5];
    const float* O     = (const float*)d_in[6];
    const float* sel_v = (const float*)d_in[7];
    const float* sel_o = (const float*)d_in[8];
    float* out = (float*)d_out;

    // workspace layout (fp32 elements)
    const size_t NELT = (size_t)NTOK * DM;   // 8388608
    float* wq   = (float*)d_ws;              // q  [B,H,S,F]
    float* wk   = wq + NELT;                 // k  [B,H,S,F]
    float* wv   = wk + NELT;                 // v  [B,H,S,F]
    float* wres = wv + NELT;                 // res[B,S,H,F]
    int*   gv_idx = (int*)(wres + NELT);
    float* gv_g1  = (float*)(gv_idx + NTOK * NH);
    float* gv_g2  = gv_g1 + NTOK * NH;
    int*   go_idx = (int*)(gv_g2 + NTOK * NH);
    float* go_g1  = (float*)(go_idx + NTOK * NH);
    float* go_g2  = go_g1 + NTOK * NH;

    // q/k projections
    dim3 pgrid(NTOK / 64, (NH * DH) / 64);
    proj_kernel<<<pgrid, 256, 0, stream>>>(q_src, Wq, wq, SCALE_SQRT);
    proj_kernel<<<pgrid, 256, 0, stream>>>(k_src, Wk, wk, SCALE_SQRT);

    // gates: gv from k_src/sel_v, go from q_src/sel_o
    gate_kernel<<<NTOK, 64, 0, stream>>>(k_src, sel_v, gv_idx, gv_g1, gv_g2);
    gate_kernel<<<NTOK, 64, 0, stream>>>(q_src, sel_o, go_idx, go_g1, go_g2);

    // value CVMM
    v_kernel<<<NTOK * NH, 128, 0, stream>>>(v_src, V, gv_idx, gv_g1, gv_g2, wv);

    // attention (flash-style): 32 bh * 32 query tiles
    attn_kernel<<<BB * NH * (SS / QT), 256, 0, stream>>>(wq, wk, wv, wres);

    // output CVMM
    out_kernel<<<NTOK, 256, 0, stream>>>(wres, O, go_idx, go_g1, go_g2, out);
}

// Round 3
// 3607.150 us; speedup vs baseline: 7.7207x; 2.7328x over previous
//
#include <hip/hip_runtime.h>
#include <hip/hip_bf16.h>
#include <math.h>

// Problem constants
#define BB 4
#define SS 2048
#define DM 1024
#define NH 8
#define DH 128
#define NE 8
#define NTOK (BB*SS)          // 8192
#define SCALE_SQRT 0.29730177875068026f

typedef unsigned short u16;
typedef short s8v __attribute__((ext_vector_type(8)));
typedef float f4v __attribute__((ext_vector_type(4)));
#define MFMA16(a,b,c) __builtin_amdgcn_mfma_f32_16x16x32_bf16((a),(b),(c),0,0,0)

// Round-to-nearest-even fp32 -> bf16 split: x ~= hi + lo (each bf16).
__device__ inline void bfsplit(float x, u16& h, u16& l) {
    unsigned u = __float_as_uint(x);
    unsigned hr = (u + 0x7FFFu + ((u >> 16) & 1u)) >> 16;
    h = (u16)hr;
    float hf = __uint_as_float(hr << 16);
    unsigned u2 = __float_as_uint(x - hf);
    l = (u16)((u2 + 0x7FFFu + ((u2 >> 16) & 1u)) >> 16);
}

// ---------------------------------------------------------------------------
// Projection GEMM (fp32, unchanged): out[b,h,s,f] = scale * A[token,:].W[hf,:]
// ---------------------------------------------------------------------------
__global__ void proj_kernel(const float* __restrict__ A,
                            const float* __restrict__ W,
                            float* __restrict__ out, float scale) {
    __shared__ float As[16][65];
    __shared__ float Ws[16][65];
    const int t  = threadIdx.x;
    const int tx = t & 15, ty = t >> 4;
    const int m0 = blockIdx.x * 64, n0 = blockIdx.y * 64;
    float acc[4][4] = {};
    for (int kt = 0; kt < DM; kt += 16) {
#pragma unroll
        for (int i = 0; i < 4; ++i) {
            int idx = t + i * 256;
            int m = idx >> 4, kk = idx & 15;
            As[kk][m] = A[(size_t)(m0 + m) * DM + kt + kk];
            Ws[kk][m] = W[(size_t)(n0 + m) * DM + kt + kk];
        }
        __syncthreads();
#pragma unroll
        for (int kk = 0; kk < 16; ++kk) {
            float a[4], b[4];
#pragma unroll
            for (int i = 0; i < 4; ++i) a[i] = As[kk][ty * 4 + i];
#pragma unroll
            for (int j = 0; j < 4; ++j) b[j] = Ws[kk][tx * 4 + j];
#pragma unroll
            for (int i = 0; i < 4; ++i)
#pragma unroll
                for (int j = 0; j < 4; ++j) acc[i][j] += a[i] * b[j];
        }
        __syncthreads();
    }
#pragma unroll
    for (int ii = 0; ii < 4; ++ii)
#pragma unroll
        for (int jj = 0; jj < 4; ++jj) {
            int i = m0 + ty * 4 + ii;
            int j = n0 + tx * 4 + jj;
            int b = i >> 11, s = i & 2047, h = j >> 7, f = j & 127;
            out[((((size_t)(b * NH + h)) * SS + s) << 7) + f] = acc[ii][jj] * scale;
        }
}

// ---------------------------------------------------------------------------
// Gate: dense sparse-valued gate g[token][h][e] (g1 at argmax of e<7, g2 at 7)
// ---------------------------------------------------------------------------
__global__ void gate_kernel(const float* __restrict__ x,
                            const float* __restrict__ sel,
                            float* __restrict__ gdense) {
    __shared__ float xs[DM];
    __shared__ float logits[64];
    __shared__ int   sbest[NH];
    __shared__ float sg1[NH], sg2[NH];
    const int token = blockIdx.x;
    const int t = threadIdx.x;  // 0..63
    const float* xp = x + (size_t)token * DM;
    for (int i = t; i < DM; i += 64) xs[i] = xp[i];
    __syncthreads();
    const float* sp = sel + (size_t)t * DM;
    float acc = 0.f;
    for (int d = 0; d < DM; ++d) acc += xs[d] * sp[d];
    logits[t] = acc;
    __syncthreads();
    if (t < NH) {
        const float* lp = logits + t * NE;
        int best = 0; float bv = lp[0];
#pragma unroll
        for (int e = 1; e < NE - 1; ++e)
            if (lp[e] > bv) { bv = lp[e]; best = e; }   // strict > == lowest idx tie
        sbest[t] = best;
        sg1[t] = 1.f / (1.f + expf(-bv));
        sg2[t] = 1.f / (1.f + expf(-lp[NE - 1]));
    }
    __syncthreads();
    const int h = t >> 3, e = t & 7;
    float val = (e == sbest[h]) ? sg1[h] : ((e == NE - 1) ? sg2[h] : 0.f);
    gdense[(size_t)token * 64 + t] = val;
}

// ---------------------------------------------------------------------------
// Preprocess: split fp32 -> bf16 hi/lo (no transpose). n divisible by 1024.
// ---------------------------------------------------------------------------
__global__ void split_kernel(const float* __restrict__ src,
                             u16* __restrict__ dh, u16* __restrict__ dl) {
    int i = (blockIdx.x * 256 + threadIdx.x) * 4;
    float4 v = *(const float4*)(src + i);
    u16 h[4], l[4];
    bfsplit(v.x, h[0], l[0]); bfsplit(v.y, h[1], l[1]);
    bfsplit(v.z, h[2], l[2]); bfsplit(v.w, h[3], l[3]);
    uint2 ph = { (unsigned)h[0] | ((unsigned)h[1] << 16),
                 (unsigned)h[2] | ((unsigned)h[3] << 16) };
    uint2 pl = { (unsigned)l[0] | ((unsigned)l[1] << 16),
                 (unsigned)l[2] | ((unsigned)l[3] << 16) };
    *(uint2*)&dh[i] = ph;
    *(uint2*)&dl[i] = pl;
}

// ---------------------------------------------------------------------------
// Preprocess: per-matrix transpose + split. src[mat][R][C] -> dst[mat][C][R].
// grid (nmat, R/32, C/32), block 256.
// ---------------------------------------------------------------------------
__global__ void tsplit_kernel(const float* __restrict__ src,
                              u16* __restrict__ dh, u16* __restrict__ dl,
                              int R, int C) {
    __shared__ float tile[32][33];
    const int mat = blockIdx.x;
    const int r0 = blockIdx.y * 32, c0 = blockIdx.z * 32;
    const size_t base = (size_t)mat * R * C;
    const int tr = threadIdx.x >> 5, tc = threadIdx.x & 31;
#pragma unroll
    for (int p = 0; p < 4; ++p)
        tile[tr + p * 8][tc] = src[base + (size_t)(r0 + tr + p * 8) * C + c0 + tc];
    __syncthreads();
#pragma unroll
    for (int p = 0; p < 4; ++p) {
        int cc = tr + p * 8, rr = tc;
        float x = tile[rr][cc];
        u16 hh, ll; bfsplit(x, hh, ll);
        size_t o = base + (size_t)(c0 + cc) * R + r0 + rr;
        dh[o] = hh; dl[o] = ll;
    }
}

// ---------------------------------------------------------------------------
// Value CVMM, split-bf16 MFMA, dense over experts.
// v[token,h,f] = sum_e g[token,h,e] * sum_d vsrc[token,d] * V[h,e,d,f]
// A = vsrc hi/lo [8192][1024]; B = Vt hi/lo [he][f][d] (pre-transposed).
// grid (m-tiles 64, h 8); block 256 (4 waves, 64x64 wave tiles); tile 128x128.
// ---------------------------------------------------------------------------
__global__ __launch_bounds__(256, 2) void v_mfma_kernel(
        const u16* __restrict__ Ah_g, const u16* __restrict__ Al_g,
        const u16* __restrict__ Bh_g, const u16* __restrict__ Bl_g,
        const float* __restrict__ gdense,
        float* __restrict__ wv) {
    const int i0 = blockIdx.x * 128;
    const int h  = blockIdx.y;
    __shared__ u16 Ah[128 * 72], Al[128 * 72], Bh[128 * 72], Bl[128 * 72];
    __shared__ float gl[128 * 8];
    const int t = threadIdx.x;
    const int lane = t & 63, wave = t >> 6;
    const int wm = wave >> 1, wn = wave & 1;
    const int ln = lane & 15, qd = lane >> 4;
    const f4v z4 = {0.f, 0.f, 0.f, 0.f};

#pragma unroll
    for (int p = 0; p < 4; ++p) {
        int idx = p * 256 + t;           // row*8 + e
        gl[idx] = gdense[(size_t)(i0 + (idx >> 3)) * 64 + h * 8 + (idx & 7)];
    }

    f4v C[4][4];
#pragma unroll
    for (int fm = 0; fm < 4; ++fm)
#pragma unroll
        for (int fn = 0; fn < 4; ++fn) C[fm][fn] = z4;

    for (int e = 0; e < 8; ++e) {
        f4v T[4][4];
#pragma unroll
        for (int fm = 0; fm < 4; ++fm)
#pragma unroll
            for (int fn = 0; fn < 4; ++fn) T[fm][fn] = z4;
        const size_t bbase = (size_t)(h * 8 + e) * DH * 1024;   // Vt[he][f][d]
        for (int kb = 0; kb < 16; ++kb) {
            __syncthreads();
            const int kbase = kb * 64;
#pragma unroll
            for (int p = 0; p < 4; ++p) {
                int chunk = p * 256 + t;
                int row = chunk >> 3, off = (chunk & 7) * 8;
                size_t ga = (size_t)(i0 + row) * 1024 + kbase + off;
                *(uint4*)&Ah[row * 72 + off] = *(const uint4*)&Ah_g[ga];
                *(uint4*)&Al[row * 72 + off] = *(const uint4*)&Al_g[ga];
                size_t gb = bbase + (size_t)row * 1024 + kbase + off;
                *(uint4*)&Bh[row * 72 + off] = *(const uint4*)&Bh_g[gb];
                *(uint4*)&Bl[row * 72 + off] = *(const uint4*)&Bl_g[gb];
            }
            __syncthreads();
#pragma unroll
            for (int ks = 0; ks < 2; ++ks) {
                s8v ah[4], alv[4], bh[4], blv[4];
#pragma unroll
                for (int fm = 0; fm < 4; ++fm) {
                    int o = (wm * 64 + fm * 16 + ln) * 72 + ks * 32 + qd * 8;
                    ah[fm]  = *(const s8v*)&Ah[o];
                    alv[fm] = *(const s8v*)&Al[o];
                }
#pragma unroll
                for (int fn = 0; fn < 4; ++fn) {
                    int o = (wn * 64 + fn * 16 + ln) * 72 + ks * 32 + qd * 8;
                    bh[fn]  = *(const s8v*)&Bh[o];
                    blv[fn] = *(const s8v*)&Bl[o];
                }
#pragma unroll
                for (int fm = 0; fm < 4; ++fm)
#pragma unroll
                    for (int fn = 0; fn < 4; ++fn) {
                        T[fm][fn] = MFMA16(ah[fm],  bh[fn],  T[fm][fn]);
                        T[fm][fn] = MFMA16(ah[fm],  blv[fn], T[fm][fn]);
                        T[fm][fn] = MFMA16(alv[fm], bh[fn],  T[fm][fn]);
                    }
            }
        }
#pragma unroll
        for (int fm = 0; fm < 4; ++fm)
#pragma unroll
            for (int r = 0; r < 4; ++r) {
                float g = gl[(wm * 64 + fm * 16 + qd * 4 + r) * 8 + e];
#pragma unroll
                for (int fn = 0; fn < 4; ++fn)
                    C[fm][fn][r] += g * T[fm][fn][r];
            }
    }
#pragma unroll
    for (int fm = 0; fm < 4; ++fm)
#pragma unroll
        for (int fn = 0; fn < 4; ++fn)
#pragma unroll
            for (int r = 0; r < 4; ++r) {
                int token = i0 + wm * 64 + fm * 16 + qd * 4 + r;
                int f = wn * 64 + fn * 16 + ln;
                int b = token >> 11, s = token & 2047;
                wv[(((size_t)(b * NH + h) * SS + s) << 7) + f] = C[fm][fn][r];
            }
}

// ---------------------------------------------------------------------------
// Output CVMM, split-bf16 MFMA, dense over (h,e).
// out[token,d] = sum_h sum_e g[token,h,e] * sum_f res[token,h,f] * O[h,e,f,d]
// A = res hi/lo [8192][1024] (k-window h*128..); B = Ot hi/lo [he][d][f].
// grid (n-tiles 8, m-tiles 64); block tile 128x128.
// ---------------------------------------------------------------------------
__global__ __launch_bounds__(256, 2) void out_mfma_kernel(
        const u16* __restrict__ Ah_g, const u16* __restrict__ Al_g,
        const u16* __restrict__ Bh_g, const u16* __restrict__ Bl_g,
        const float* __restrict__ gdense,
        float* __restrict__ out) {
    const int n0 = blockIdx.x * 128;
    const int i0 = blockIdx.y * 128;
    __shared__ u16 Ah[128 * 72], Al[128 * 72], Bh[128 * 72], Bl[128 * 72];
    __shared__ float gl[128 * 8];
    const int t = threadIdx.x;
    const int lane = t & 63, wave = t >> 6;
    const int wm = wave >> 1, wn = wave & 1;
    const int ln = lane & 15, qd = lane >> 4;
    const f4v z4 = {0.f, 0.f, 0.f, 0.f};

    f4v C[4][4];
#pragma unroll
    for (int fm = 0; fm < 4; ++fm)
#pragma unroll
        for (int fn = 0; fn < 4; ++fn) C[fm][fn] = z4;

    for (int h = 0; h < 8; ++h) {
        __syncthreads();     // prev h epilogue done before gl overwrite
#pragma unroll
        for (int p = 0; p < 4; ++p) {
            int idx = p * 256 + t;
            gl[idx] = gdense[(size_t)(i0 + (idx >> 3)) * 64 + h * 8 + (idx & 7)];
        }
        for (int e = 0; e < 8; ++e) {
            f4v T[4][4];
#pragma unroll
            for (int fm = 0; fm < 4; ++fm)
#pragma unroll
                for (int fn = 0; fn < 4; ++fn) T[fm][fn] = z4;
            const size_t bbase = ((size_t)(h * 8 + e) * 1024 + n0) * DH; // Ot[he][d][f]
#pragma unroll
            for (int kb = 0; kb < 2; ++kb) {
                __syncthreads();
                const int ka = h * 128 + kb * 64;
                const int kbb = kb * 64;
#pragma unroll
                for (int p = 0; p < 4; ++p) {
                    int chunk = p * 256 + t;
                    int row = chunk >> 3, off = (chunk & 7) * 8;
                    size_t ga = (size_t)(i0 + row) * 1024 + ka + off;
                    *(uint4*)&Ah[row * 72 + off] = *(const uint4*)&Ah_g[ga];
                    *(uint4*)&Al[row * 72 + off] = *(const uint4*)&Al_g[ga];
                    size_t gb = bbase + (size_t)row * DH + kbb + off;
                    *(uint4*)&Bh[row * 72 + off] = *(const uint4*)&Bh_g[gb];
                    *(uint4*)&Bl[row * 72 + off] = *(const uint4*)&Bl_g[gb];
                }
                __syncthreads();
#pragma unroll
                for (int ks = 0; ks < 2; ++ks) {
                    s8v ah[4], alv[4], bh[4], blv[4];
#pragma unroll
                    for (int fm = 0; fm < 4; ++fm) {
                        int o = (wm * 64 + fm * 16 + ln) * 72 + ks * 32 + qd * 8;
                        ah[fm]  = *(const s8v*)&Ah[o];
                        alv[fm] = *(const s8v*)&Al[o];
                    }
#pragma unroll
                    for (int fn = 0; fn < 4; ++fn) {
                        int o = (wn * 64 + fn * 16 + ln) * 72 + ks * 32 + qd * 8;
                        bh[fn]  = *(const s8v*)&Bh[o];
                        blv[fn] = *(const s8v*)&Bl[o];
                    }
#pragma unroll
                    for (int fm = 0; fm < 4; ++fm)
#pragma unroll
                        for (int fn = 0; fn < 4; ++fn) {
                            T[fm][fn] = MFMA16(ah[fm],  bh[fn],  T[fm][fn]);
                            T[fm][fn] = MFMA16(ah[fm],  blv[fn], T[fm][fn]);
                            T[fm][fn] = MFMA16(alv[fm], bh[fn],  T[fm][fn]);
                        }
                }
            }
#pragma unroll
            for (int fm = 0; fm < 4; ++fm)
#pragma unroll
                for (int r = 0; r < 4; ++r) {
                    float g = gl[(wm * 64 + fm * 16 + qd * 4 + r) * 8 + e];
#pragma unroll
                    for (int fn = 0; fn < 4; ++fn)
                        C[fm][fn][r] += g * T[fm][fn][r];
                }
        }
    }
#pragma unroll
    for (int fm = 0; fm < 4; ++fm)
#pragma unroll
        for (int fn = 0; fn < 4; ++fn)
#pragma unroll
            for (int r = 0; r < 4; ++r) {
                int token = i0 + wm * 64 + fm * 16 + qd * 4 + r;
                int d = n0 + wn * 64 + fn * 16 + ln;
                out[(size_t)token * DM + d] = C[fm][fn][r];
            }
}

// ---------------------------------------------------------------------------
// Flash-style attention, fp32; epilogue writes res as bf16 hi/lo.
// ---------------------------------------------------------------------------
#define QT 64
#define KT 32

__global__ __launch_bounds__(256, 2) void attn_kernel(
        const float* __restrict__ q,
        const float* __restrict__ k,
        const float* __restrict__ v,
        u16* __restrict__ res_hi,
        u16* __restrict__ res_lo) {
    const int bid = blockIdx.x;
    const int bh = bid >> 5;
    const int q0 = (bid & 31) * QT;

    __shared__ float Qs[DH][QT];
    __shared__ float KPbuf[DH * KT];     // Ks[f*KT+j] / Ps[j*68+i]
    __shared__ float Vs[KT][DH];
    __shared__ float mArr[QT], lArr[QT], aArr[QT];
    __shared__ float red[4][QT];

    const int t = threadIdx.x;
    const int tx = t & 15, ty = t >> 4;

    const float* qp = q + ((size_t)bh * SS + q0) * DH;
#pragma unroll
    for (int r = 0; r < 8; ++r) {
        int idx = r * 256 + t;
        int i = idx >> 5;
        int f4 = (idx & 31) << 2;
        float4 qv = *(const float4*)(qp + (size_t)i * DH + f4);
        Qs[f4 + 0][i] = qv.x; Qs[f4 + 1][i] = qv.y;
        Qs[f4 + 2][i] = qv.z; Qs[f4 + 3][i] = qv.w;
    }
    if (t < QT) { mArr[t] = -INFINITY; lArr[t] = 0.f; }

    float O[4][8];
#pragma unroll
    for (int ii = 0; ii < 4; ++ii)
#pragma unroll
        for (int cc = 0; cc < 8; ++cc) O[ii][cc] = 0.f;

    const float* kbase = k + (size_t)bh * SS * DH;
    const float* vbase = v + (size_t)bh * SS * DH;

    for (int kt = 0; kt < SS / KT; ++kt) {
        __syncthreads();
        const float* kp = kbase + (size_t)kt * KT * DH;
        const float* vp = vbase + (size_t)kt * KT * DH;
#pragma unroll
        for (int r = 0; r < 4; ++r) {
            int idx = r * 256 + t;
            int j = idx >> 5;
            int f4 = (idx & 31) << 2;
            float4 kv = *(const float4*)(kp + (size_t)j * DH + f4);
            KPbuf[(f4 + 0) * KT + j] = kv.x; KPbuf[(f4 + 1) * KT + j] = kv.y;
            KPbuf[(f4 + 2) * KT + j] = kv.z; KPbuf[(f4 + 3) * KT + j] = kv.w;
            float4 vv = *(const float4*)(vp + (size_t)j * DH + f4);
            *(float4*)&Vs[j][f4] = vv;
        }
        __syncthreads();

        float s[4][2] = {};
#pragma unroll 8
        for (int f = 0; f < DH; ++f) {
            float4 a = *(const float4*)&Qs[f][ty * 4];
            float2 b = *(const float2*)&KPbuf[f * KT + tx * 2];
            s[0][0] += a.x * b.x; s[0][1] += a.x * b.y;
            s[1][0] += a.y * b.x; s[1][1] += a.y * b.y;
            s[2][0] += a.z * b.x; s[2][1] += a.z * b.y;
            s[3][0] += a.w * b.x; s[3][1] += a.w * b.y;
        }
        __syncthreads();

#pragma unroll
        for (int jj = 0; jj < 2; ++jj)
#pragma unroll
            for (int ii = 0; ii < 4; ++ii)
                KPbuf[(tx * 2 + jj) * 68 + ty * 4 + ii] = s[ii][jj];
        __syncthreads();

        if (t < QT) {
            float mx = -INFINITY;
#pragma unroll
            for (int j = 0; j < KT; ++j) mx = fmaxf(mx, KPbuf[j * 68 + t]);
            float mo = mArr[t];
            float mn = fmaxf(mo, mx);
            mArr[t] = mn;
            aArr[t] = __expf(mo - mn);
        }
        __syncthreads();

#pragma unroll
        for (int ii = 0; ii < 4; ++ii) {
            float al = aArr[ty * 4 + ii];
#pragma unroll
            for (int cc = 0; cc < 8; ++cc) O[ii][cc] *= al;
        }
        {
            int i = t & 63, jg = t >> 6;
            float mi = mArr[i];
            float sum = 0.f;
#pragma unroll
            for (int jj = 0; jj < 8; ++jj) {
                int j = jg * 8 + jj;
                float p = __expf(KPbuf[j * 68 + i] - mi);
                KPbuf[j * 68 + i] = p;
                sum += p;
            }
            red[jg][i] = sum;
        }
        __syncthreads();
        if (t < QT)
            lArr[t] = aArr[t] * lArr[t] + red[0][t] + red[1][t] + red[2][t] + red[3][t];

#pragma unroll 4
        for (int j = 0; j < KT; ++j) {
            float4 p4 = *(const float4*)&KPbuf[j * 68 + ty * 4];
            float4 v0 = *(const float4*)&Vs[j][tx * 8];
            float4 v1 = *(const float4*)&Vs[j][tx * 8 + 4];
            float pv[4] = {p4.x, p4.y, p4.z, p4.w};
#pragma unroll
            for (int ii = 0; ii < 4; ++ii) {
                O[ii][0] += pv[ii] * v0.x; O[ii][1] += pv[ii] * v0.y;
                O[ii][2] += pv[ii] * v0.z; O[ii][3] += pv[ii] * v0.w;
                O[ii][4] += pv[ii] * v1.x; O[ii][5] += pv[ii] * v1.y;
                O[ii][6] += pv[ii] * v1.z; O[ii][7] += pv[ii] * v1.w;
            }
        }
    }
    __syncthreads();

    const int b = bh >> 3, h = bh & 7;
#pragma unroll
    for (int ii = 0; ii < 4; ++ii) {
        float linv = 1.f / lArr[ty * 4 + ii];
        int qi = q0 + ty * 4 + ii;
        float o[8];
#pragma unroll
        for (int cc = 0; cc < 8; ++cc) o[cc] = O[ii][cc] * linv;
        u16 hh[8], ll[8];
#pragma unroll
        for (int cc = 0; cc < 8; ++cc) bfsplit(o[cc], hh[cc], ll[cc]);
        size_t off = (size_t)(b * SS + qi) * DM + h * DH + tx * 8;
        uint4 ph = { (unsigned)hh[0] | ((unsigned)hh[1] << 16),
                     (unsigned)hh[2] | ((unsigned)hh[3] << 16),
                     (unsigned)hh[4] | ((unsigned)hh[5] << 16),
                     (unsigned)hh[6] | ((unsigned)hh[7] << 16) };
        uint4 pl = { (unsigned)ll[0] | ((unsigned)ll[1] << 16),
                     (unsigned)ll[2] | ((unsigned)ll[3] << 16),
                     (unsigned)ll[4] | ((unsigned)ll[5] << 16),
                     (unsigned)ll[6] | ((unsigned)ll[7] << 16) };
        *(uint4*)&res_hi[off] = ph;
        *(uint4*)&res_lo[off] = pl;
    }
}

// ---------------------------------------------------------------------------
extern "C" void kernel_launch(void* const* d_in, const int* in_sizes, int n_in,
                              void* d_out, int out_size, void* d_ws, size_t ws_size,
                              hipStream_t stream) {
    (void)in_sizes; (void)n_in; (void)out_size; (void)ws_size;
    const float* q_src = (const float*)d_in[0];
    const float* k_src = (const float*)d_in[1];
    const float* v_src = (const float*)d_in[2];
    const float* Wq    = (const float*)d_in[3];
    const float* Wk    = (const float*)d_in[4];
    const float* V     = (const float*)d_in[5];
    const float* O     = (const float*)d_in[6];
    const float* sel_v = (const float*)d_in[7];
    const float* sel_o = (const float*)d_in[8];
    float* out = (float*)d_out;

    // workspace layout
    const size_t NELT = (size_t)NTOK * DM;   // 8388608
    float* wq = (float*)d_ws;                // [B,H,S,F] fp32
    float* wk = wq + NELT;
    float* wv = wk + NELT;
    u16* res_hi = (u16*)(wv + NELT);         // [8192][1024] bf16 hi/lo
    u16* res_lo = res_hi + NELT;
    u16* vs_hi  = res_lo + NELT;             // vsrc split
    u16* vs_lo  = vs_hi + NELT;
    u16* Vt_hi  = vs_lo + NELT;              // V transposed [he][f][d]
    u16* Vt_lo  = Vt_hi + NELT;
    u16* Ot_hi  = vs_hi;                     // alias: O transposed (after v_kernel)
    u16* Ot_lo  = vs_lo;
    float* gv = (float*)(Vt_lo + NELT);      // dense gates [8192][8][8]
    float* go = gv + (size_t)NTOK * 64;

    // preprocess: split v_src; transpose+split V
    split_kernel<<<NELT / 1024, 256, 0, stream>>>(v_src, vs_hi, vs_lo);
    tsplit_kernel<<<dim3(64, 32, 4), 256, 0, stream>>>(V, Vt_hi, Vt_lo, 1024, 128);

    // gates
    gate_kernel<<<NTOK, 64, 0, stream>>>(k_src, sel_v, gv);
    gate_kernel<<<NTOK, 64, 0, stream>>>(q_src, sel_o, go);

    // q/k projections
    dim3 pgrid(NTOK / 64, (NH * DH) / 64);
    proj_kernel<<<pgrid, 256, 0, stream>>>(q_src, Wq, wq, SCALE_SQRT);
    proj_kernel<<<pgrid, 256, 0, stream>>>(k_src, Wk, wk, SCALE_SQRT);

    // value CVMM (MFMA)
    v_mfma_kernel<<<dim3(64, 8), 256, 0, stream>>>(vs_hi, vs_lo, Vt_hi, Vt_lo, gv, wv);

    // transpose+split O into the (now dead) vsrc-split buffers
    tsplit_kernel<<<dim3(64, 4, 32), 256, 0, stream>>>(O, Ot_hi, Ot_lo, 128, 1024);

    // attention (res written as bf16 hi/lo)
    attn_kernel<<<BB * NH * (SS / QT), 256, 0, stream>>>(wq, wk, wv, res_hi, res_lo);

    // output CVMM (MFMA)
    out_mfma_kernel<<<dim3(8, 64), 256, 0, stream>>>(res_hi, res_lo, Ot_hi, Ot_lo, go, out);
}

// Round 4
// 2768.160 us; speedup vs baseline: 10.0608x; 1.3031x over previous
//
#include <hip/hip_runtime.h>
#include <hip/hip_bf16.h>
#include <math.h>

// Problem constants
#define BB 4
#define SS 2048
#define DM 1024
#define NH 8
#define DH 128
#define NE 8
#define NTOK (BB*SS)          // 8192
#define SCALE_SQRT 0.29730177875068026f

typedef unsigned short u16;
typedef short s8v __attribute__((ext_vector_type(8)));
typedef float f4v __attribute__((ext_vector_type(4)));
#define MFMA16(a,b,c) __builtin_amdgcn_mfma_f32_16x16x32_bf16((a),(b),(c),0,0,0)

// Round-to-nearest-even fp32 -> bf16 split: x ~= hi + lo (each bf16).
__device__ inline void bfsplit(float x, u16& h, u16& l) {
    unsigned u = __float_as_uint(x);
    unsigned hr = (u + 0x7FFFu + ((u >> 16) & 1u)) >> 16;
    h = (u16)hr;
    float hf = __uint_as_float(hr << 16);
    unsigned u2 = __float_as_uint(x - hf);
    l = (u16)((u2 + 0x7FFFu + ((u2 >> 16) & 1u)) >> 16);
}
__device__ inline u16 bf16rne(float x) {
    unsigned u = __float_as_uint(x);
    return (u16)((u + 0x7FFFu + ((u >> 16) & 1u)) >> 16);
}

// ---------------------------------------------------------------------------
// Projection GEMM (fp32 accumulate): emits bf16 hi/lo directly.
// out[bh][s][f] = scale * A[token,:].W[h*128+f,:]
// ---------------------------------------------------------------------------
__global__ void proj_kernel(const float* __restrict__ A,
                            const float* __restrict__ W,
                            u16* __restrict__ out_h, u16* __restrict__ out_l,
                            float scale) {
    __shared__ float As[16][65];
    __shared__ float Ws[16][65];
    const int t  = threadIdx.x;
    const int tx = t & 15, ty = t >> 4;
    const int m0 = blockIdx.x * 64, n0 = blockIdx.y * 64;
    float acc[4][4] = {};
    for (int kt = 0; kt < DM; kt += 16) {
#pragma unroll
        for (int i = 0; i < 4; ++i) {
            int idx = t + i * 256;
            int m = idx >> 4, kk = idx & 15;
            As[kk][m] = A[(size_t)(m0 + m) * DM + kt + kk];
            Ws[kk][m] = W[(size_t)(n0 + m) * DM + kt + kk];
        }
        __syncthreads();
#pragma unroll
        for (int kk = 0; kk < 16; ++kk) {
            float a[4], b[4];
#pragma unroll
            for (int i = 0; i < 4; ++i) a[i] = As[kk][ty * 4 + i];
#pragma unroll
            for (int j = 0; j < 4; ++j) b[j] = Ws[kk][tx * 4 + j];
#pragma unroll
            for (int i = 0; i < 4; ++i)
#pragma unroll
                for (int j = 0; j < 4; ++j) acc[i][j] += a[i] * b[j];
        }
        __syncthreads();
    }
#pragma unroll
    for (int ii = 0; ii < 4; ++ii)
#pragma unroll
        for (int jj = 0; jj < 4; ++jj) {
            int i = m0 + ty * 4 + ii;
            int j = n0 + tx * 4 + jj;
            int b = i >> 11, s = i & 2047, h = j >> 7, f = j & 127;
            u16 hh, ll;
            bfsplit(acc[ii][jj] * scale, hh, ll);
            size_t o = ((((size_t)(b * NH + h)) * SS + s) << 7) + f;
            out_h[o] = hh; out_l[o] = ll;
        }
}

// ---------------------------------------------------------------------------
// Gate: dense sparse-valued gate g[token][h][e]
// ---------------------------------------------------------------------------
__global__ void gate_kernel(const float* __restrict__ x,
                            const float* __restrict__ sel,
                            float* __restrict__ gdense) {
    __shared__ float xs[DM];
    __shared__ float logits[64];
    __shared__ int   sbest[NH];
    __shared__ float sg1[NH], sg2[NH];
    const int token = blockIdx.x;
    const int t = threadIdx.x;  // 0..63
    const float* xp = x + (size_t)token * DM;
    for (int i = t; i < DM; i += 64) xs[i] = xp[i];
    __syncthreads();
    const float* sp = sel + (size_t)t * DM;
    float acc = 0.f;
    for (int d = 0; d < DM; ++d) acc += xs[d] * sp[d];
    logits[t] = acc;
    __syncthreads();
    if (t < NH) {
        const float* lp = logits + t * NE;
        int best = 0; float bv = lp[0];
#pragma unroll
        for (int e = 1; e < NE - 1; ++e)
            if (lp[e] > bv) { bv = lp[e]; best = e; }   // strict > == lowest idx tie
        sbest[t] = best;
        sg1[t] = 1.f / (1.f + expf(-bv));
        sg2[t] = 1.f / (1.f + expf(-lp[NE - 1]));
    }
    __syncthreads();
    const int h = t >> 3, e = t & 7;
    float val = (e == sbest[h]) ? sg1[h] : ((e == NE - 1) ? sg2[h] : 0.f);
    gdense[(size_t)token * 64 + t] = val;
}

// ---------------------------------------------------------------------------
// Preprocess: split fp32 -> bf16 hi/lo (no transpose). n divisible by 1024.
// ---------------------------------------------------------------------------
__global__ void split_kernel(const float* __restrict__ src,
                             u16* __restrict__ dh, u16* __restrict__ dl) {
    int i = (blockIdx.x * 256 + threadIdx.x) * 4;
    float4 v = *(const float4*)(src + i);
    u16 h[4], l[4];
    bfsplit(v.x, h[0], l[0]); bfsplit(v.y, h[1], l[1]);
    bfsplit(v.z, h[2], l[2]); bfsplit(v.w, h[3], l[3]);
    uint2 ph = { (unsigned)h[0] | ((unsigned)h[1] << 16),
                 (unsigned)h[2] | ((unsigned)h[3] << 16) };
    uint2 pl = { (unsigned)l[0] | ((unsigned)l[1] << 16),
                 (unsigned)l[2] | ((unsigned)l[3] << 16) };
    *(uint2*)&dh[i] = ph;
    *(uint2*)&dl[i] = pl;
}

// ---------------------------------------------------------------------------
// Preprocess: per-matrix transpose + split. src[mat][R][C] -> dst[mat][C][R].
// grid (nmat, R/32, C/32), block 256.
// ---------------------------------------------------------------------------
__global__ void tsplit_kernel(const float* __restrict__ src,
                              u16* __restrict__ dh, u16* __restrict__ dl,
                              int R, int C) {
    __shared__ float tile[32][33];
    const int mat = blockIdx.x;
    const int r0 = blockIdx.y * 32, c0 = blockIdx.z * 32;
    const size_t base = (size_t)mat * R * C;
    const int tr = threadIdx.x >> 5, tc = threadIdx.x & 31;
#pragma unroll
    for (int p = 0; p < 4; ++p)
        tile[tr + p * 8][tc] = src[base + (size_t)(r0 + tr + p * 8) * C + c0 + tc];
    __syncthreads();
#pragma unroll
    for (int p = 0; p < 4; ++p) {
        int cc = tr + p * 8, rr = tc;
        float x = tile[rr][cc];
        u16 hh, ll; bfsplit(x, hh, ll);
        size_t o = base + (size_t)(c0 + cc) * R + r0 + rr;
        dh[o] = hh; dl[o] = ll;
    }
}

// ---------------------------------------------------------------------------
// Value CVMM, split-bf16 MFMA, dense over experts (unchanged).
// ---------------------------------------------------------------------------
__global__ __launch_bounds__(256, 2) void v_mfma_kernel(
        const u16* __restrict__ Ah_g, const u16* __restrict__ Al_g,
        const u16* __restrict__ Bh_g, const u16* __restrict__ Bl_g,
        const float* __restrict__ gdense,
        float* __restrict__ wv) {
    const int i0 = blockIdx.x * 128;
    const int h  = blockIdx.y;
    __shared__ u16 Ah[128 * 72], Al[128 * 72], Bh[128 * 72], Bl[128 * 72];
    __shared__ float gl[128 * 8];
    const int t = threadIdx.x;
    const int lane = t & 63, wave = t >> 6;
    const int wm = wave >> 1, wn = wave & 1;
    const int ln = lane & 15, qd = lane >> 4;
    const f4v z4 = {0.f, 0.f, 0.f, 0.f};

#pragma unroll
    for (int p = 0; p < 4; ++p) {
        int idx = p * 256 + t;
        gl[idx] = gdense[(size_t)(i0 + (idx >> 3)) * 64 + h * 8 + (idx & 7)];
    }

    f4v C[4][4];
#pragma unroll
    for (int fm = 0; fm < 4; ++fm)
#pragma unroll
        for (int fn = 0; fn < 4; ++fn) C[fm][fn] = z4;

    for (int e = 0; e < 8; ++e) {
        f4v T[4][4];
#pragma unroll
        for (int fm = 0; fm < 4; ++fm)
#pragma unroll
            for (int fn = 0; fn < 4; ++fn) T[fm][fn] = z4;
        const size_t bbase = (size_t)(h * 8 + e) * DH * 1024;
        for (int kb = 0; kb < 16; ++kb) {
            __syncthreads();
            const int kbase = kb * 64;
#pragma unroll
            for (int p = 0; p < 4; ++p) {
                int chunk = p * 256 + t;
                int row = chunk >> 3, off = (chunk & 7) * 8;
                size_t ga = (size_t)(i0 + row) * 1024 + kbase + off;
                *(uint4*)&Ah[row * 72 + off] = *(const uint4*)&Ah_g[ga];
                *(uint4*)&Al[row * 72 + off] = *(const uint4*)&Al_g[ga];
                size_t gb = bbase + (size_t)row * 1024 + kbase + off;
                *(uint4*)&Bh[row * 72 + off] = *(const uint4*)&Bh_g[gb];
                *(uint4*)&Bl[row * 72 + off] = *(const uint4*)&Bl_g[gb];
            }
            __syncthreads();
#pragma unroll
            for (int ks = 0; ks < 2; ++ks) {
                s8v ah[4], alv[4], bh[4], blv[4];
#pragma unroll
                for (int fm = 0; fm < 4; ++fm) {
                    int o = (wm * 64 + fm * 16 + ln) * 72 + ks * 32 + qd * 8;
                    ah[fm]  = *(const s8v*)&Ah[o];
                    alv[fm] = *(const s8v*)&Al[o];
                }
#pragma unroll
                for (int fn = 0; fn < 4; ++fn) {
                    int o = (wn * 64 + fn * 16 + ln) * 72 + ks * 32 + qd * 8;
                    bh[fn]  = *(const s8v*)&Bh[o];
                    blv[fn] = *(const s8v*)&Bl[o];
                }
#pragma unroll
                for (int fm = 0; fm < 4; ++fm)
#pragma unroll
                    for (int fn = 0; fn < 4; ++fn) {
                        T[fm][fn] = MFMA16(ah[fm],  bh[fn],  T[fm][fn]);
                        T[fm][fn] = MFMA16(ah[fm],  blv[fn], T[fm][fn]);
                        T[fm][fn] = MFMA16(alv[fm], bh[fn],  T[fm][fn]);
                    }
            }
        }
#pragma unroll
        for (int fm = 0; fm < 4; ++fm)
#pragma unroll
            for (int r = 0; r < 4; ++r) {
                float g = gl[(wm * 64 + fm * 16 + qd * 4 + r) * 8 + e];
#pragma unroll
                for (int fn = 0; fn < 4; ++fn)
                    C[fm][fn][r] += g * T[fm][fn][r];
            }
    }
#pragma unroll
    for (int fm = 0; fm < 4; ++fm)
#pragma unroll
        for (int fn = 0; fn < 4; ++fn)
#pragma unroll
            for (int r = 0; r < 4; ++r) {
                int token = i0 + wm * 64 + fm * 16 + qd * 4 + r;
                int f = wn * 64 + fn * 16 + ln;
                int b = token >> 11, s = token & 2047;
                wv[(((size_t)(b * NH + h) * SS + s) << 7) + f] = C[fm][fn][r];
            }
}

// ---------------------------------------------------------------------------
// Output CVMM, split-bf16 MFMA, dense over (h,e) (unchanged).
// ---------------------------------------------------------------------------
__global__ __launch_bounds__(256, 2) void out_mfma_kernel(
        const u16* __restrict__ Ah_g, const u16* __restrict__ Al_g,
        const u16* __restrict__ Bh_g, const u16* __restrict__ Bl_g,
        const float* __restrict__ gdense,
        float* __restrict__ out) {
    const int n0 = blockIdx.x * 128;
    const int i0 = blockIdx.y * 128;
    __shared__ u16 Ah[128 * 72], Al[128 * 72], Bh[128 * 72], Bl[128 * 72];
    __shared__ float gl[128 * 8];
    const int t = threadIdx.x;
    const int lane = t & 63, wave = t >> 6;
    const int wm = wave >> 1, wn = wave & 1;
    const int ln = lane & 15, qd = lane >> 4;
    const f4v z4 = {0.f, 0.f, 0.f, 0.f};

    f4v C[4][4];
#pragma unroll
    for (int fm = 0; fm < 4; ++fm)
#pragma unroll
        for (int fn = 0; fn < 4; ++fn) C[fm][fn] = z4;

    for (int h = 0; h < 8; ++h) {
        __syncthreads();
#pragma unroll
        for (int p = 0; p < 4; ++p) {
            int idx = p * 256 + t;
            gl[idx] = gdense[(size_t)(i0 + (idx >> 3)) * 64 + h * 8 + (idx & 7)];
        }
        for (int e = 0; e < 8; ++e) {
            f4v T[4][4];
#pragma unroll
            for (int fm = 0; fm < 4; ++fm)
#pragma unroll
                for (int fn = 0; fn < 4; ++fn) T[fm][fn] = z4;
            const size_t bbase = ((size_t)(h * 8 + e) * 1024 + n0) * DH;
#pragma unroll
            for (int kb = 0; kb < 2; ++kb) {
                __syncthreads();
                const int ka = h * 128 + kb * 64;
                const int kbb = kb * 64;
#pragma unroll
                for (int p = 0; p < 4; ++p) {
                    int chunk = p * 256 + t;
                    int row = chunk >> 3, off = (chunk & 7) * 8;
                    size_t ga = (size_t)(i0 + row) * 1024 + ka + off;
                    *(uint4*)&Ah[row * 72 + off] = *(const uint4*)&Ah_g[ga];
                    *(uint4*)&Al[row * 72 + off] = *(const uint4*)&Al_g[ga];
                    size_t gb = bbase + (size_t)row * DH + kbb + off;
                    *(uint4*)&Bh[row * 72 + off] = *(const uint4*)&Bh_g[gb];
                    *(uint4*)&Bl[row * 72 + off] = *(const uint4*)&Bl_g[gb];
                }
                __syncthreads();
#pragma unroll
                for (int ks = 0; ks < 2; ++ks) {
                    s8v ah[4], alv[4], bh[4], blv[4];
#pragma unroll
                    for (int fm = 0; fm < 4; ++fm) {
                        int o = (wm * 64 + fm * 16 + ln) * 72 + ks * 32 + qd * 8;
                        ah[fm]  = *(const s8v*)&Ah[o];
                        alv[fm] = *(const s8v*)&Al[o];
                    }
#pragma unroll
                    for (int fn = 0; fn < 4; ++fn) {
                        int o = (wn * 64 + fn * 16 + ln) * 72 + ks * 32 + qd * 8;
                        bh[fn]  = *(const s8v*)&Bh[o];
                        blv[fn] = *(const s8v*)&Bl[o];
                    }
#pragma unroll
                    for (int fm = 0; fm < 4; ++fm)
#pragma unroll
                        for (int fn = 0; fn < 4; ++fn) {
                            T[fm][fn] = MFMA16(ah[fm],  bh[fn],  T[fm][fn]);
                            T[fm][fn] = MFMA16(ah[fm],  blv[fn], T[fm][fn]);
                            T[fm][fn] = MFMA16(alv[fm], bh[fn],  T[fm][fn]);
                        }
                }
            }
#pragma unroll
            for (int fm = 0; fm < 4; ++fm)
#pragma unroll
                for (int r = 0; r < 4; ++r) {
                    float g = gl[(wm * 64 + fm * 16 + qd * 4 + r) * 8 + e];
#pragma unroll
                    for (int fn = 0; fn < 4; ++fn)
                        C[fm][fn][r] += g * T[fm][fn][r];
                }
        }
    }
#pragma unroll
    for (int fm = 0; fm < 4; ++fm)
#pragma unroll
        for (int fn = 0; fn < 4; ++fn)
#pragma unroll
            for (int r = 0; r < 4; ++r) {
                int token = i0 + wm * 64 + fm * 16 + qd * 4 + r;
                int d = n0 + wn * 64 + fn * 16 + ln;
                out[(size_t)token * DM + d] = C[fm][fn][r];
            }
}

// ---------------------------------------------------------------------------
// MFMA flash attention. Block = (b,h) x 64 queries; 4 waves, 16 q-rows each.
// K-tiles of 64; online softmax fully in registers (quad shuffles).
//   Q: A-frags preloaded in registers (hi+lo) from global (layout matches).
//   K: staged [j][f] hi/lo, stride 136 u16  (B-operand for QK, 3-term split).
//   V: pre-transposed vT[bh][f][s]; staged [f][j] hi/lo, stride 72 u16
//      (B-operand for PV, P single-bf16 x V hi/lo).
//   P: per-wave 16x64 LDS round-trip (C-layout -> A-layout), stride 72.
// LDS total 80896 B.
// ---------------------------------------------------------------------------
__global__ void attn_mfma_kernel(
        const u16* __restrict__ qh, const u16* __restrict__ ql,
        const u16* __restrict__ kh, const u16* __restrict__ kl,
        const u16* __restrict__ vth, const u16* __restrict__ vtl,
        u16* __restrict__ res_hi, u16* __restrict__ res_lo) {
    const int bid = blockIdx.x;          // bh*32 + qtile
    const int bh = bid >> 5;
    const int q0 = (bid & 31) * 64;

    __shared__ u16 Ksh[64 * 136];
    __shared__ u16 Ksl[64 * 136];
    __shared__ u16 Vsh[128 * 72];
    __shared__ u16 Vsl[128 * 72];
    __shared__ u16 Ps[4][16 * 72];

    const int t = threadIdx.x;
    const int lane = t & 63, w = t >> 6;
    const int ln = lane & 15, qd = lane >> 4;

    // Q A-fragments in registers (m = ln, k = ks*32 + qd*8 + 0..7)
    s8v Qh[4], Qlv[4];
    {
        const size_t qoff = ((size_t)bh * SS + q0 + w * 16 + ln) * DH;
        const u16* qhp = qh + qoff;
        const u16* qlp = ql + qoff;
#pragma unroll
        for (int ks = 0; ks < 4; ++ks) {
            Qh[ks]  = *(const s8v*)(qhp + ks * 32 + qd * 8);
            Qlv[ks] = *(const s8v*)(qlp + ks * 32 + qd * 8);
        }
    }

    f4v Of[8];
    const f4v z4 = {0.f, 0.f, 0.f, 0.f};
#pragma unroll
    for (int fn = 0; fn < 8; ++fn) Of[fn] = z4;
    float mrow[4], lrow[4];
#pragma unroll
    for (int r = 0; r < 4; ++r) { mrow[r] = -INFINITY; lrow[r] = 0.f; }

    const u16* kbh = kh + (size_t)bh * SS * DH;
    const u16* kbl = kl + (size_t)bh * SS * DH;
    const u16* vbh = vth + (size_t)bh * DH * SS;   // [f][s]
    const u16* vbl = vtl + (size_t)bh * DH * SS;

    for (int kt = 0; kt < SS / 64; ++kt) {
        __syncthreads();   // all waves done with previous K/V tiles
        // ---- stage K [64 rows x 128] and V [128 rows x 64] hi/lo ----
#pragma unroll
        for (int p = 0; p < 4; ++p) {
            int chunk = p * 256 + t;
            int krow = chunk >> 4, kc = chunk & 15;
            size_t g = (size_t)(kt * 64 + krow) * DH + kc * 8;
            *(uint4*)&Ksh[krow * 136 + kc * 8] = *(const uint4*)&kbh[g];
            *(uint4*)&Ksl[krow * 136 + kc * 8] = *(const uint4*)&kbl[g];
            int vrow = chunk >> 3, vc = chunk & 7;
            size_t gv = (size_t)vrow * SS + kt * 64 + vc * 8;
            *(uint4*)&Vsh[vrow * 72 + vc * 8] = *(const uint4*)&vbh[gv];
            *(uint4*)&Vsl[vrow * 72 + vc * 8] = *(const uint4*)&vbl[gv];
        }
        __syncthreads();

        // ---- QK^T: S[nt] covers cols nt*16+ln, rows qd*4+r ----
        f4v S[4];
#pragma unroll
        for (int nt = 0; nt < 4; ++nt) S[nt] = z4;
#pragma unroll
        for (int ks = 0; ks < 4; ++ks) {
#pragma unroll
            for (int nt = 0; nt < 4; ++nt) {
                int o = (nt * 16 + ln) * 136 + ks * 32 + qd * 8;
                s8v kbhf = *(const s8v*)&Ksh[o];
                s8v kblf = *(const s8v*)&Ksl[o];
                S[nt] = MFMA16(Qh[ks],  kbhf, S[nt]);
                S[nt] = MFMA16(Qh[ks],  kblf, S[nt]);
                S[nt] = MFMA16(Qlv[ks], kbhf, S[nt]);
            }
        }

        // ---- online softmax in registers (rows qd*4+r, 16 lanes = 64 cols) --
        float mt[4];
#pragma unroll
        for (int r = 0; r < 4; ++r) {
            mt[r] = fmaxf(fmaxf(S[0][r], S[1][r]), fmaxf(S[2][r], S[3][r]));
        }
#pragma unroll
        for (int mask = 1; mask < 16; mask <<= 1)
#pragma unroll
            for (int r = 0; r < 4; ++r)
                mt[r] = fmaxf(mt[r], __shfl_xor(mt[r], mask, 64));
        float alpha[4];
#pragma unroll
        for (int r = 0; r < 4; ++r) {
            float mn = fmaxf(mrow[r], mt[r]);
            alpha[r] = __expf(mrow[r] - mn);
            mrow[r] = mn;
        }
        float pv[4][4], lt[4] = {0.f, 0.f, 0.f, 0.f};
#pragma unroll
        for (int nt = 0; nt < 4; ++nt)
#pragma unroll
            for (int r = 0; r < 4; ++r) {
                float p = __expf(S[nt][r] - mrow[r]);
                pv[nt][r] = p;
                lt[r] += p;
            }
#pragma unroll
        for (int mask = 1; mask < 16; mask <<= 1)
#pragma unroll
            for (int r = 0; r < 4; ++r)
                lt[r] += __shfl_xor(lt[r], mask, 64);
#pragma unroll
        for (int r = 0; r < 4; ++r) lrow[r] = alpha[r] * lrow[r] + lt[r];
#pragma unroll
        for (int fn = 0; fn < 8; ++fn)
#pragma unroll
            for (int r = 0; r < 4; ++r) Of[fn][r] *= alpha[r];

        // ---- P (C-layout) -> per-wave LDS (A-layout source) ----
#pragma unroll
        for (int nt = 0; nt < 4; ++nt)
#pragma unroll
            for (int r = 0; r < 4; ++r)
                Ps[w][(qd * 4 + r) * 72 + nt * 16 + ln] = bf16rne(pv[nt][r]);
        // same-wave write->read: compiler inserts lgkmcnt wait; no barrier.

        // ---- PV: Of += P * V (V split hi/lo) ----
#pragma unroll
        for (int ks2 = 0; ks2 < 2; ++ks2) {
            s8v pf = *(const s8v*)&Ps[w][ln * 72 + ks2 * 32 + qd * 8];
#pragma unroll
            for (int fn = 0; fn < 8; ++fn) {
                int o = (fn * 16 + ln) * 72 + ks2 * 32 + qd * 8;
                s8v vbhf = *(const s8v*)&Vsh[o];
                s8v vblf = *(const s8v*)&Vsl[o];
                Of[fn] = MFMA16(pf, vbhf, Of[fn]);
                Of[fn] = MFMA16(pf, vblf, Of[fn]);
            }
        }
    }

    // ---- epilogue: normalize, split to bf16 hi/lo, store res[token][1024] --
    const int b = bh >> 3, h = bh & 7;
#pragma unroll
    for (int r = 0; r < 4; ++r) {
        float linv = 1.f / lrow[r];
        int qi = q0 + w * 16 + qd * 4 + r;
        size_t off = (size_t)(b * SS + qi) * DM + h * DH + ln;
#pragma unroll
        for (int fn = 0; fn < 8; ++fn) {
            u16 hh, ll;
            bfsplit(Of[fn][r] * linv, hh, ll);
            res_hi[off + fn * 16] = hh;
            res_lo[off + fn * 16] = ll;
        }
    }
}

// ---------------------------------------------------------------------------
extern "C" void kernel_launch(void* const* d_in, const int* in_sizes, int n_in,
                              void* d_out, int out_size, void* d_ws, size_t ws_size,
                              hipStream_t stream) {
    (void)in_sizes; (void)n_in; (void)out_size; (void)ws_size;
    const float* q_src = (const float*)d_in[0];
    const float* k_src = (const float*)d_in[1];
    const float* v_src = (const float*)d_in[2];
    const float* Wq    = (const float*)d_in[3];
    const float* Wk    = (const float*)d_in[4];
    const float* V     = (const float*)d_in[5];
    const float* O     = (const float*)d_in[6];
    const float* sel_v = (const float*)d_in[7];
    const float* sel_o = (const float*)d_in[8];
    float* out = (float*)d_out;

    // workspace layout
    const size_t NELT = (size_t)NTOK * DM;   // 8388608
    u16* wq_h = (u16*)d_ws;                  // q hi/lo [bh][s][f]
    u16* wq_l = wq_h + NELT;
    u16* wk_h = wq_l + NELT;                 // k hi/lo
    u16* wk_l = wk_h + NELT;
    float* wv = (float*)(wk_l + NELT);       // v fp32 [bh][s][f]
    u16* res_hi = (u16*)(wv + NELT);         // attention result hi/lo
    u16* res_lo = res_hi + NELT;
    u16* vs_hi  = res_lo + NELT;             // vsrc split (later: Ot)
    u16* vs_lo  = vs_hi + NELT;
    u16* Vt_hi  = vs_lo + NELT;              // V transposed (later: vT)
    u16* Vt_lo  = Vt_hi + NELT;
    float* gv = (float*)(Vt_lo + NELT);      // dense gates [8192][64]
    float* go = gv + (size_t)NTOK * 64;
    u16* Ot_hi = vs_hi;                      // alias (dead after v_mfma)
    u16* Ot_lo = vs_lo;
    u16* vth   = Vt_hi;                      // alias (dead after v_mfma)
    u16* vtl   = Vt_lo;

    // preprocess
    split_kernel<<<NELT / 1024, 256, 0, stream>>>(v_src, vs_hi, vs_lo);
    tsplit_kernel<<<dim3(64, 32, 4), 256, 0, stream>>>(V, Vt_hi, Vt_lo, 1024, 128);

    // gates
    gate_kernel<<<NTOK, 64, 0, stream>>>(k_src, sel_v, gv);
    gate_kernel<<<NTOK, 64, 0, stream>>>(q_src, sel_o, go);

    // q/k projections (emit bf16 hi/lo)
    dim3 pgrid(NTOK / 64, (NH * DH) / 64);
    proj_kernel<<<pgrid, 256, 0, stream>>>(q_src, Wq, wq_h, wq_l, SCALE_SQRT);
    proj_kernel<<<pgrid, 256, 0, stream>>>(k_src, Wk, wk_h, wk_l, SCALE_SQRT);

    // value CVMM (MFMA) -> wv fp32
    v_mfma_kernel<<<dim3(64, 8), 256, 0, stream>>>(vs_hi, vs_lo, Vt_hi, Vt_lo, gv, wv);

    // transpose+split O into dead vsrc buffers
    tsplit_kernel<<<dim3(64, 4, 32), 256, 0, stream>>>(O, Ot_hi, Ot_lo, 128, 1024);

    // transpose+split v into dead Vt buffers: vT[bh][f][s]
    tsplit_kernel<<<dim3(32, 64, 4), 256, 0, stream>>>(wv, vth, vtl, 2048, 128);

    // attention (MFMA flash)
    attn_mfma_kernel<<<BB * NH * (SS / 64), 256, 0, stream>>>(
        wq_h, wq_l, wk_h, wk_l, vth, vtl, res_hi, res_lo);

    // output CVMM (MFMA)
    out_mfma_kernel<<<dim3(8, 64), 256, 0, stream>>>(res_hi, res_lo, Ot_hi, Ot_lo, go, out);
}